// Round 1
// baseline (850.882 us; speedup 1.0000x reference)
//
#include <hip/hip_runtime.h>
#include <stdint.h>

#define B_ 4
#define HC 256
#define WC 256
#define C_ 128
#define HF 512
#define WF 512
#define NPTS 8192
#define HIDDEN_ 256
#define NPIX (HC*WC)
#define PPB 32
#define FSTRIDE 132

// ---------------- copy coarse -> out ----------------
__global__ void pr_copy_kernel(const float4* __restrict__ src, float4* __restrict__ dst, int n4) {
    int i = blockIdx.x * blockDim.x + threadIdx.x;
    if (i < n4) dst[i] = src[i];
}

// ---------------- per-batch radix select of NPTS smallest |coarse| ----------------
__global__ __launch_bounds__(1024) void pr_select_kernel(const float* __restrict__ coarse,
                                                         int* __restrict__ sel) {
    int b = blockIdx.x;
    const float* cb = coarse + (size_t)b * NPIX;
    int tid = threadIdx.x;
    __shared__ unsigned hist[256];
    __shared__ unsigned s_prefix;
    __shared__ int s_remk;
    __shared__ unsigned warp_eq[16];
    __shared__ unsigned s_eqbase;
    __shared__ unsigned s_outcnt;

    if (tid == 0) { s_prefix = 0u; s_remk = NPTS; s_eqbase = 0u; s_outcnt = 0u; }

    for (int pass = 0; pass < 4; ++pass) {
        if (tid < 256) hist[tid] = 0u;
        __syncthreads();
        unsigned prefix = s_prefix;
        int shift = 24 - 8 * pass;
        for (int i = tid; i < NPIX; i += 1024) {
            unsigned k = __float_as_uint(cb[i]) & 0x7fffffffu;
            bool cond = (pass == 0) || ((k >> (shift + 8)) == prefix);
            if (cond) atomicAdd(&hist[(k >> shift) & 0xffu], 1u);
        }
        __syncthreads();
        if (tid == 0) {
            unsigned c = 0; int remk = s_remk; int chosen = 0;
            for (int bin = 0; bin < 256; ++bin) {
                unsigned h = hist[bin];
                if ((unsigned)remk <= c + h) { chosen = bin; break; }
                c += h;
            }
            s_prefix = (s_prefix << 8) | (unsigned)chosen;
            s_remk = remk - (int)c;
        }
        __syncthreads();
    }

    unsigned T = s_prefix;          // exact key value of the NPTS-th smallest
    unsigned need_eq = (unsigned)s_remk;  // how many ties (== T) to take, smallest index first
    int lane = tid & 63, wid = tid >> 6;
    for (int base = 0; base < NPIX; base += 1024) {
        int i = base + tid;
        unsigned k = __float_as_uint(cb[i]) & 0x7fffffffu;
        bool lt = (k < T);
        bool eq = (k == T);
        unsigned long long m = __ballot(eq);
        if (lane == 0) warp_eq[wid] = (unsigned)__popcll(m);
        __syncthreads();
        unsigned wbase = 0, tot = 0;
        for (int w = 0; w < 16; ++w) { unsigned h = warp_eq[w]; if (w < wid) wbase += h; tot += h; }
        unsigned rank = s_eqbase + wbase + (unsigned)__popcll(m & ((1ull << lane) - 1ull));
        bool take = lt || (eq && rank < need_eq);
        if (take) {
            unsigned pos = atomicAdd(&s_outcnt, 1u);
            sel[b * NPTS + pos] = i;
        }
        __syncthreads();
        if (tid == 0) s_eqbase += tot;
        // s_eqbase is re-read only after next iteration's __syncthreads()
    }
}

// ---------------- gather + MLP + scatter ----------------
__global__ __launch_bounds__(256) void pr_mlp_kernel(
    const float* __restrict__ coarse, const float* __restrict__ fine,
    const float* __restrict__ W1, const float* __restrict__ b1,
    const float* __restrict__ W2, const float* __restrict__ b2,
    const int* __restrict__ sel, float* __restrict__ out) {

    __shared__ float feats[PPB * FSTRIDE];
    __shared__ int sidx[PPB];
    __shared__ float red[PPB][4];

    int tid = threadIdx.x;
    const int bpb = NPTS / PPB;               // blocks per batch
    int b = blockIdx.x / bpb;
    int pbase = (blockIdx.x % bpb) * PPB;

    if (tid < PPB) sidx[tid] = sel[b * NPTS + pbase + tid];
    __syncthreads();

    const float* fb = fine + (size_t)b * C_ * HF * WF;
    int c = tid & 127;
    int ph = tid >> 7;                        // 2 points per iteration
    for (int it = 0; it < PPB / 2; ++it) {
        int p = 2 * it + ph;
        int id = sidx[p];
        int ix = id & (WC - 1), iy = id >> 8;
        const float* a = fb + (size_t)c * (HF * WF) + (size_t)(2 * iy) * WF + 2 * ix;
        float2 r0 = *(const float2*)a;
        float2 r1 = *(const float2*)(a + WF);
        feats[p * FSTRIDE + c] = 0.25f * ((r0.x + r0.y) + (r1.x + r1.y));
    }
    if (tid < PPB) feats[tid * FSTRIDE + 128] = coarse[(size_t)b * NPIX + sidx[tid]];
    __syncthreads();

    // layer 1: thread j computes hid[j] for all PPB points
    int j = tid;
    float acc[PPB];
    float b1j = b1[j];
#pragma unroll
    for (int p = 0; p < PPB; ++p) acc[p] = b1j;

    const float4* fs4 = (const float4*)feats;
    for (int f4 = 0; f4 < 32; ++f4) {
        float w0 = W1[(4 * f4 + 0) * HIDDEN_ + j];
        float w1 = W1[(4 * f4 + 1) * HIDDEN_ + j];
        float w2 = W1[(4 * f4 + 2) * HIDDEN_ + j];
        float w3 = W1[(4 * f4 + 3) * HIDDEN_ + j];
#pragma unroll
        for (int p = 0; p < PPB; ++p) {
            float4 fv = fs4[p * (FSTRIDE / 4) + f4];
            acc[p] = fmaf(fv.x, w0, acc[p]);
            acc[p] = fmaf(fv.y, w1, acc[p]);
            acc[p] = fmaf(fv.z, w2, acc[p]);
            acc[p] = fmaf(fv.w, w3, acc[p]);
        }
    }
    {
        float w128 = W1[128 * HIDDEN_ + j];
#pragma unroll
        for (int p = 0; p < PPB; ++p) acc[p] = fmaf(feats[p * FSTRIDE + 128], w128, acc[p]);
    }

    // layer 2: relu + dot with W2, reduce across 256 threads
    float w2j = W2[j];
    int lane = tid & 63, wid = tid >> 6;
#pragma unroll
    for (int p = 0; p < PPB; ++p) {
        float v = fmaxf(acc[p], 0.0f) * w2j;
        v += __shfl_down(v, 32, 64);
        v += __shfl_down(v, 16, 64);
        v += __shfl_down(v, 8, 64);
        v += __shfl_down(v, 4, 64);
        v += __shfl_down(v, 2, 64);
        v += __shfl_down(v, 1, 64);
        if (lane == 0) red[p][wid] = v;
    }
    __syncthreads();
    if (tid < PPB) {
        float r = red[tid][0] + red[tid][1] + red[tid][2] + red[tid][3] + b2[0];
        out[(size_t)b * NPIX + sidx[tid]] = r;
    }
}

extern "C" void kernel_launch(void* const* d_in, const int* in_sizes, int n_in,
                              void* d_out, int out_size, void* d_ws, size_t ws_size,
                              hipStream_t stream) {
    const float* coarse = (const float*)d_in[0];
    const float* fine   = (const float*)d_in[1];
    const float* W1     = (const float*)d_in[2];
    const float* b1     = (const float*)d_in[3];
    const float* W2     = (const float*)d_in[4];
    const float* b2     = (const float*)d_in[5];
    float* out = (float*)d_out;
    int* sel = (int*)d_ws;   // B_ * NPTS ints = 128 KB scratch

    int n4 = B_ * NPIX / 4;
    pr_copy_kernel<<<(n4 + 255) / 256, 256, 0, stream>>>((const float4*)coarse, (float4*)out, n4);
    pr_select_kernel<<<B_, 1024, 0, stream>>>(coarse, sel);
    pr_mlp_kernel<<<B_ * (NPTS / PPB), 256, 0, stream>>>(coarse, fine, W1, b1, W2, b2, sel, out);
}

// Round 2
// 796.966 us; speedup vs baseline: 1.0677x; 1.0677x over previous
//
#include <hip/hip_runtime.h>
#include <stdint.h>

#define B_ 4
#define HC 256
#define WC 256
#define C_ 128
#define HF 512
#define WF 512
#define NPTS 8192
#define HIDDEN_ 256
#define NPIX (HC*WC)
#define PPB 16
#define FSTRIDE 132

// ---------------- copy coarse -> out ----------------
__global__ void pr_copy_kernel(const float4* __restrict__ src, float4* __restrict__ dst, int n4) {
    int i = blockIdx.x * blockDim.x + threadIdx.x;
    if (i < n4) dst[i] = src[i];
}

// ---------------- per-batch radix select of NPTS smallest |coarse|, ordered output ----------------
__global__ __launch_bounds__(1024) void pr_select_kernel(const float* __restrict__ coarse,
                                                         int* __restrict__ sel) {
    int b = blockIdx.x;
    const float* cb = coarse + (size_t)b * NPIX;
    int tid = threadIdx.x;
    int lane = tid & 63, wid = tid >> 6;

    __shared__ unsigned hist[256];
    __shared__ unsigned s_prefix;
    __shared__ int s_remk;
    __shared__ unsigned wsum[16];
    __shared__ unsigned s_chosen, s_cless;
    __shared__ unsigned warp_eq[16], warp_take[16];
    __shared__ unsigned s_eqbase, s_outbase;

    if (tid == 0) { s_prefix = 0u; s_remk = NPTS; }

    for (int pass = 0; pass < 4; ++pass) {
        if (tid < 256) hist[tid] = 0u;
        __syncthreads();
        unsigned prefix = s_prefix;
        int remk = s_remk;
        int shift = 24 - 8 * pass;

        if (pass == 0) {
            // keys concentrate in ~4 exponent bins -> wave-aggregated atomics
            for (int i = 4 * tid; i < NPIX; i += 4096) {
                float4 v = *(const float4*)(cb + i);
                unsigned bins[4];
                bins[0] = (__float_as_uint(v.x) & 0x7fffffffu) >> 24;
                bins[1] = (__float_as_uint(v.y) & 0x7fffffffu) >> 24;
                bins[2] = (__float_as_uint(v.z) & 0x7fffffffu) >> 24;
                bins[3] = (__float_as_uint(v.w) & 0x7fffffffu) >> 24;
#pragma unroll
                for (int e = 0; e < 4; ++e) {
                    unsigned bin = bins[e];
                    unsigned long long am = ~0ull;
                    while (am) {
                        int leader = __ffsll((unsigned long long)am) - 1;
                        unsigned lbin = __shfl(bin, leader, 64);
                        unsigned long long match = __ballot(bin == lbin);
                        if (lane == leader) atomicAdd(&hist[lbin], (unsigned)__popcll(match));
                        am &= ~match;
                    }
                }
            }
        } else {
            for (int i = 4 * tid; i < NPIX; i += 4096) {
                float4 v = *(const float4*)(cb + i);
                unsigned k0 = __float_as_uint(v.x) & 0x7fffffffu;
                unsigned k1 = __float_as_uint(v.y) & 0x7fffffffu;
                unsigned k2 = __float_as_uint(v.z) & 0x7fffffffu;
                unsigned k3 = __float_as_uint(v.w) & 0x7fffffffu;
                if ((k0 >> (shift + 8)) == prefix) atomicAdd(&hist[(k0 >> shift) & 0xffu], 1u);
                if ((k1 >> (shift + 8)) == prefix) atomicAdd(&hist[(k1 >> shift) & 0xffu], 1u);
                if ((k2 >> (shift + 8)) == prefix) atomicAdd(&hist[(k2 >> shift) & 0xffu], 1u);
                if ((k3 >> (shift + 8)) == prefix) atomicAdd(&hist[(k3 >> shift) & 0xffu], 1u);
            }
        }
        __syncthreads();

        // parallel choose: inclusive scan over 256 bins (threads 0..255)
        unsigned h = 0, incl = 0;
        if (tid < 256) {
            h = hist[tid];
            incl = h;
#pragma unroll
            for (int d = 1; d < 64; d <<= 1) {
                unsigned y = __shfl_up(incl, d, 64);
                if (lane >= d) incl += y;
            }
            if (lane == 63) wsum[wid] = incl;
        }
        __syncthreads();
        if (tid < 256) {
            unsigned base = 0;
            for (int w = 0; w < wid; ++w) base += wsum[w];
            unsigned inc = base + incl;
            unsigned exc = inc - h;
            if ((unsigned)remk > exc && (unsigned)remk <= inc) { s_chosen = (unsigned)tid; s_cless = exc; }
        }
        __syncthreads();
        if (tid == 0) { s_prefix = (s_prefix << 8) | s_chosen; s_remk = remk - (int)s_cless; }
        __syncthreads();
    }

    unsigned T = s_prefix;                 // key value of the NPTS-th smallest
    unsigned need_eq = (unsigned)s_remk;   // # of ==T ties to take, smallest index first
    if (tid == 0) { s_eqbase = 0u; s_outbase = 0u; }
    __syncthreads();

    unsigned long long ltmask = (1ull << lane) - 1ull;
    for (int base = 0; base < NPIX; base += 4096) {
        int i0 = base + 4 * tid;
        float4 v = *(const float4*)(cb + i0);
        unsigned k[4];
        k[0] = __float_as_uint(v.x) & 0x7fffffffu;
        k[1] = __float_as_uint(v.y) & 0x7fffffffu;
        k[2] = __float_as_uint(v.z) & 0x7fffffffu;
        k[3] = __float_as_uint(v.w) & 0x7fffffffu;
        bool lt[4], eq[4];
        unsigned long long me[4];
        unsigned weq = 0;
#pragma unroll
        for (int e = 0; e < 4; ++e) {
            lt[e] = k[e] < T;
            eq[e] = k[e] == T;
            me[e] = __ballot(eq[e]);
            weq += (unsigned)__popcll(me[e]);
        }
        if (lane == 0) warp_eq[wid] = weq;
        __syncthreads();

        unsigned eqwb = 0, eqtot = 0;
        for (int w = 0; w < 16; ++w) { unsigned hh = warp_eq[w]; if (w < wid) eqwb += hh; eqtot += hh; }
        unsigned lt_lanes_eq = 0;
#pragma unroll
        for (int e = 0; e < 4; ++e) lt_lanes_eq += (unsigned)__popcll(me[e] & ltmask);
        unsigned ebase = s_eqbase + eqwb + lt_lanes_eq;

        bool take[4];
        unsigned long long mt[4];
        unsigned self_eq = 0;
#pragma unroll
        for (int e = 0; e < 4; ++e) {
            unsigned eqrank = ebase + self_eq;
            take[e] = lt[e] || (eq[e] && eqrank < need_eq);
            self_eq += eq[e] ? 1u : 0u;
        }
        unsigned wtk = 0;
#pragma unroll
        for (int e = 0; e < 4; ++e) {
            mt[e] = __ballot(take[e]);
            wtk += (unsigned)__popcll(mt[e]);
        }
        if (lane == 0) warp_take[wid] = wtk;
        __syncthreads();

        unsigned twb = 0, ttot = 0;
        for (int w = 0; w < 16; ++w) { unsigned hh = warp_take[w]; if (w < wid) twb += hh; ttot += hh; }
        unsigned lt_lanes_tk = 0;
#pragma unroll
        for (int e = 0; e < 4; ++e) lt_lanes_tk += (unsigned)__popcll(mt[e] & ltmask);
        unsigned tbase = s_outbase + twb + lt_lanes_tk;
        unsigned self_tk = 0;
#pragma unroll
        for (int e = 0; e < 4; ++e) {
            if (take[e]) sel[b * NPTS + (int)(tbase + self_tk)] = i0 + e;
            self_tk += take[e] ? 1u : 0u;
        }
        __syncthreads();
        if (tid == 0) { s_eqbase += eqtot; s_outbase += ttot; }
        // next read of s_eqbase/s_outbase is after the next iteration's first __syncthreads
    }
}

// ---------------- gather + MLP + scatter ----------------
__global__ __launch_bounds__(256) void pr_mlp_kernel(
    const float* __restrict__ coarse, const float* __restrict__ fine,
    const float* __restrict__ W1, const float* __restrict__ b1,
    const float* __restrict__ W2, const float* __restrict__ b2,
    const int* __restrict__ sel, float* __restrict__ out) {

    __shared__ __align__(16) float feats[PPB * FSTRIDE];
    __shared__ int sidx[PPB];
    __shared__ float red[PPB][4];

    int tid = threadIdx.x;
    const int bpb = NPTS / PPB;               // 512 blocks per batch
    int b = blockIdx.x / bpb;
    int pbase = (blockIdx.x % bpb) * PPB;

    if (tid < PPB) sidx[tid] = sel[b * NPTS + pbase + tid];
    __syncthreads();

    const float* fb = fine + (size_t)b * (C_ * HF * WF);
    int c = tid & 127;
    int ph = tid >> 7;                        // 2 points per k-step

    // issue ALL 16 gather loads before any LDS write (latency hiding)
    float2 r0[PPB / 2], r1[PPB / 2];
#pragma unroll
    for (int k = 0; k < PPB / 2; ++k) {
        int p = 2 * k + ph;
        int id = sidx[p];
        int ix = id & (WC - 1), iy = id >> 8;
        const float* a = fb + (size_t)c * (HF * WF) + (size_t)(2 * iy) * WF + 2 * ix;
        r0[k] = *(const float2*)a;
        r1[k] = *(const float2*)(a + WF);
    }
#pragma unroll
    for (int k = 0; k < PPB / 2; ++k) {
        int p = 2 * k + ph;
        feats[p * FSTRIDE + c] = 0.25f * ((r0[k].x + r0[k].y) + (r1[k].x + r1[k].y));
    }
    if (tid < PPB) feats[tid * FSTRIDE + 128] = coarse[(size_t)b * NPIX + sidx[tid]];
    __syncthreads();

    // layer 1: thread j computes hid[j] for all PPB points
    int j = tid;
    float acc[PPB];
    float b1j = b1[j];
#pragma unroll
    for (int p = 0; p < PPB; ++p) acc[p] = b1j;

    const float4* fs4 = (const float4*)feats;
#pragma unroll 4
    for (int f4 = 0; f4 < 32; ++f4) {
        float w0 = W1[(4 * f4 + 0) * HIDDEN_ + j];
        float w1 = W1[(4 * f4 + 1) * HIDDEN_ + j];
        float w2 = W1[(4 * f4 + 2) * HIDDEN_ + j];
        float w3 = W1[(4 * f4 + 3) * HIDDEN_ + j];
#pragma unroll
        for (int p = 0; p < PPB; ++p) {
            float4 fv = fs4[p * (FSTRIDE / 4) + f4];
            acc[p] = fmaf(fv.x, w0, acc[p]);
            acc[p] = fmaf(fv.y, w1, acc[p]);
            acc[p] = fmaf(fv.z, w2, acc[p]);
            acc[p] = fmaf(fv.w, w3, acc[p]);
        }
    }
    {
        float w128 = W1[128 * HIDDEN_ + j];
#pragma unroll
        for (int p = 0; p < PPB; ++p) acc[p] = fmaf(feats[p * FSTRIDE + 128], w128, acc[p]);
    }

    // layer 2: relu + dot with W2, reduce across 256 threads
    float w2j = W2[j];
    int lane = tid & 63, wid = tid >> 6;
#pragma unroll
    for (int p = 0; p < PPB; ++p) {
        float v = fmaxf(acc[p], 0.0f) * w2j;
        v += __shfl_down(v, 32, 64);
        v += __shfl_down(v, 16, 64);
        v += __shfl_down(v, 8, 64);
        v += __shfl_down(v, 4, 64);
        v += __shfl_down(v, 2, 64);
        v += __shfl_down(v, 1, 64);
        if (lane == 0) red[p][wid] = v;
    }
    __syncthreads();
    if (tid < PPB) {
        float r = red[tid][0] + red[tid][1] + red[tid][2] + red[tid][3] + b2[0];
        out[(size_t)b * NPIX + sidx[tid]] = r;
    }
}

extern "C" void kernel_launch(void* const* d_in, const int* in_sizes, int n_in,
                              void* d_out, int out_size, void* d_ws, size_t ws_size,
                              hipStream_t stream) {
    const float* coarse = (const float*)d_in[0];
    const float* fine   = (const float*)d_in[1];
    const float* W1     = (const float*)d_in[2];
    const float* b1     = (const float*)d_in[3];
    const float* W2     = (const float*)d_in[4];
    const float* b2     = (const float*)d_in[5];
    float* out = (float*)d_out;
    int* sel = (int*)d_ws;   // B_ * NPTS ints = 128 KB scratch

    int n4 = B_ * NPIX / 4;
    pr_copy_kernel<<<(n4 + 255) / 256, 256, 0, stream>>>((const float4*)coarse, (float4*)out, n4);
    pr_select_kernel<<<B_, 1024, 0, stream>>>(coarse, sel);
    pr_mlp_kernel<<<B_ * (NPTS / PPB), 256, 0, stream>>>(coarse, fine, W1, b1, W2, b2, sel, out);
}